// Round 6
// baseline (50.600 us; speedup 1.0000x reference)
//
#include <hip/hip_runtime.h>
#include <stdint.h>

#define BATCH   32768
#define NBITS   512
#define NWORDS  512          // BATCH / 64
#define NSLICE  16           // K-split: 136 tiles * 16 = 2176 one-wave blocks
#define SW      32           // words per slice = NWORDS / NSLICE
#define NT32    136          // 16x17/2 lower-triangle of 32x32 tiles
#define MIGRID  512          // mi blocks

typedef unsigned long long u64;

// ---------------------------------------------------------------------------
// Pass 1: bit-pack + f64 log table + zero c1/done.
// 2048 wave-tasks: wave = (word w, column-quarter q); lane reads float2,
// builds two u64 row-masks, ulonglong2 store. 64 MB @ ~6.5 TB/s ~ 10 us.
// ---------------------------------------------------------------------------
__global__ __launch_bounds__(256) void pack_kernel(const float* __restrict__ bits,
                                                   u64* __restrict__ packed,
                                                   double* __restrict__ lg,
                                                   int* __restrict__ c1,
                                                   int* __restrict__ done) {
    const int gid = blockIdx.x * 256 + threadIdx.x;   // 0..131071

    if (gid <= BATCH) lg[gid] = (gid > 0) ? log((double)gid) : 0.0;
    if (gid < NBITS) c1[gid] = 0;
    if (gid == NBITS) *done = 0;

    const int wv   = threadIdx.x >> 6;
    const int lane = threadIdx.x & 63;
    const int gw   = blockIdx.x * 4 + wv;     // 0..2047
    const int w    = gw >> 2;                 // word 0..511
    const int q    = gw & 3;                  // column quarter
    const int c0   = q * 128 + lane * 2;

    u64 m0 = 0, m1 = 0;
    const float* base = bits + (size_t)w * 64 * NBITS + c0;
#pragma unroll 16
    for (int r = 0; r < 64; ++r) {
        float2 v = *reinterpret_cast<const float2*>(base + (size_t)r * NBITS);
        const u64 b = 1ull << r;
        if (v.x > 0.0f) m0 |= b;
        if (v.y > 0.0f) m1 |= b;
    }
    ulonglong2 st; st.x = m0; st.y = m1;
    *reinterpret_cast<ulonglong2*>(&packed[(size_t)w * NBITS + c0]) = st;
}

// ---------------------------------------------------------------------------
// Pass 2: partial Gram, VALU-bound shape. Block = 1 wave (64 threads),
// (tile t of 136 [32x32], slice s of 16 [32 words]). Thread grid 8x8, 4x4
// register tile: per word 4 ds_read_b128 feed 16 popcll -> 4 B LDS/term.
// 2176 blocks, 16 KB LDS each (~9 resident/CU). Plain int4 stores into
// Cp[s]; diagonal tiles accumulate c1 via integer atomics (exact).
// ---------------------------------------------------------------------------
__global__ __launch_bounds__(64) void gram_kernel(const u64* __restrict__ packed,
                                                  int* __restrict__ Cp,
                                                  int* __restrict__ c1) {
    __shared__ u64 ldsI[SW][32];
    __shared__ u64 ldsJ[SW][32];

    const int s = blockIdx.x & (NSLICE - 1);  // K-slice 0..15
    const int t = blockIdx.x >> 4;            // tile 0..135
    int bi = (int)((sqrtf(8.0f * (float)t + 1.0f) - 1.0f) * 0.5f);
    while ((bi + 1) * (bi + 2) / 2 <= t) ++bi;
    while (bi * (bi + 1) / 2 > t) --bi;
    const int bj = t - bi * (bi + 1) / 2;

    const int i0 = bi * 32, j0 = bj * 32;
    const int w0 = s * SW;
    const bool diag = (bi == bj);

    // stage 32 words x 32 cols per side (8 KB each)
    for (int q = threadIdx.x; q < SW * 16; q += 64) {
        const int wo = q >> 4, cp = (q & 15) * 2;
        const size_t g = (size_t)(w0 + wo) * NBITS;
        *reinterpret_cast<ulonglong2*>(&ldsI[wo][cp]) =
            *reinterpret_cast<const ulonglong2*>(&packed[g + i0 + cp]);
        if (!diag)
            *reinterpret_cast<ulonglong2*>(&ldsJ[wo][cp]) =
                *reinterpret_cast<const ulonglong2*>(&packed[g + j0 + cp]);
    }
    __syncthreads();

    const int tx4 = (threadIdx.x & 7) * 4;    // b-cols (j side)
    const int ty4 = (threadIdx.x >> 3) * 4;   // a-cols (i side)
    const u64 (*BJ)[32] = diag ? ldsI : ldsJ;

    int acc[4][4] = {};
#pragma unroll 4
    for (int w = 0; w < SW; ++w) {
        const u64 a0 = ldsI[w][ty4],     a1 = ldsI[w][ty4 + 1];
        const u64 a2 = ldsI[w][ty4 + 2], a3 = ldsI[w][ty4 + 3];
        const u64 b0 = BJ[w][tx4],       b1 = BJ[w][tx4 + 1];
        const u64 b2 = BJ[w][tx4 + 2],   b3 = BJ[w][tx4 + 3];
        acc[0][0] += __popcll(a0 & b0); acc[0][1] += __popcll(a0 & b1);
        acc[0][2] += __popcll(a0 & b2); acc[0][3] += __popcll(a0 & b3);
        acc[1][0] += __popcll(a1 & b0); acc[1][1] += __popcll(a1 & b1);
        acc[1][2] += __popcll(a1 & b2); acc[1][3] += __popcll(a1 & b3);
        acc[2][0] += __popcll(a2 & b0); acc[2][1] += __popcll(a2 & b1);
        acc[2][2] += __popcll(a2 & b2); acc[2][3] += __popcll(a2 & b3);
        acc[3][0] += __popcll(a3 & b0); acc[3][1] += __popcll(a3 & b1);
        acc[3][2] += __popcll(a3 & b2); acc[3][3] += __popcll(a3 & b3);
    }

    int* out = Cp + (size_t)s * NBITS * NBITS;
#pragma unroll
    for (int a = 0; a < 4; ++a)
        *reinterpret_cast<int4*>(&out[(size_t)(i0 + ty4 + a) * NBITS + j0 + tx4]) =
            make_int4(acc[a][0], acc[a][1], acc[a][2], acc[a][3]);

    if (diag && tx4 == ty4) {
#pragma unroll
        for (int a = 0; a < 4; ++a)
            atomicAdd(&c1[i0 + ty4 + a], acc[a][a]);
    }
}

// ---------------------------------------------------------------------------
// Pass 3 (+fused final): per-pair MI terms. Block i, thread j (+256). n11 =
// coalesced sum of 16 slice partials of row i; marginals from c1. Log-table
// epilogue, deterministic block reduction -> bsum/bcnt. The LAST block to
// finish (threadfence + done counter) reduces all 512 partials and writes out.
// ---------------------------------------------------------------------------
__global__ __launch_bounds__(256) void mi_kernel(const int* __restrict__ Cp,
                                                 const int* __restrict__ c1,
                                                 const double* __restrict__ lg,
                                                 double* __restrict__ bsum,
                                                 int* __restrict__ bcnt,
                                                 int* __restrict__ done,
                                                 float* __restrict__ out) {
    const double invB = 1.0 / (double)BATCH;
    const int i = blockIdx.x;
    const int ci = c1[i];
    const double lgB = lg[BATCH];
    double lsum = 0.0;
    int lcnt = 0;

#pragma unroll
    for (int half = 0; half < 2; ++half) {
        const int j = half * 256 + threadIdx.x;
        if (j < i) {
            int n11 = 0;
#pragma unroll
            for (int s = 0; s < NSLICE; ++s)
                n11 += Cp[(size_t)s * NBITS * NBITS + (size_t)i * NBITS + j];
            const int cj = c1[j];

            const int pim[2] = {BATCH - ci, ci};
            const int pjn[2] = {BATCH - cj, cj};
            const int nmn[2][2] = {{BATCH - ci - cj + n11, cj - n11},
                                   {ci - n11, n11}};
#pragma unroll
            for (int m = 0; m < 2; ++m)
#pragma unroll
                for (int n = 0; n < 2; ++n) {
                    const int c_mn = nmn[m][n];
                    if (c_mn > 0 && pim[m] > 0 && pjn[n] > 0) {
                        lsum += (double)c_mn * invB *
                                (lg[c_mn] + lgB - lg[pim[m]] - lg[pjn[n]]);
                        ++lcnt;
                    }
                }
        }
    }

    __shared__ double ssum[256];
    __shared__ int scnt[256];
    __shared__ int lastFlag;
    ssum[threadIdx.x] = lsum;
    scnt[threadIdx.x] = lcnt;
    __syncthreads();
    for (int off = 128; off > 0; off >>= 1) {
        if (threadIdx.x < off) {
            ssum[threadIdx.x] += ssum[threadIdx.x + off];
            scnt[threadIdx.x] += scnt[threadIdx.x + off];
        }
        __syncthreads();
    }
    if (threadIdx.x == 0) {
        bsum[i] = ssum[0];
        bcnt[i] = scnt[0];
        __threadfence();
        lastFlag = (atomicAdd(done, 1) == MIGRID - 1);
    }
    __syncthreads();
    if (!lastFlag) return;

    // last block: reduce the 512 partials (deterministic order)
    __threadfence();
    double s2 = bsum[threadIdx.x] + bsum[threadIdx.x + 256];
    int c2 = bcnt[threadIdx.x] + bcnt[threadIdx.x + 256];
    __syncthreads();
    ssum[threadIdx.x] = s2;
    scnt[threadIdx.x] = c2;
    __syncthreads();
    for (int off = 128; off > 0; off >>= 1) {
        if (threadIdx.x < off) {
            ssum[threadIdx.x] += ssum[threadIdx.x + off];
            scnt[threadIdx.x] += scnt[threadIdx.x + off];
        }
        __syncthreads();
    }
    if (threadIdx.x == 0) out[0] = (float)(ssum[0] / (double)scnt[0]);
}

// ---------------------------------------------------------------------------
extern "C" void kernel_launch(void* const* d_in, const int* in_sizes, int n_in,
                              void* d_out, int out_size, void* d_ws, size_t ws_size,
                              hipStream_t stream) {
    const float* bits = (const float*)d_in[0];
    char* ws = (char*)d_ws;
    u64*    packed = (u64*)ws;                                   // 2 MB
    int*    Cp     = (int*)(ws + (2u << 20));                    // 16 x 1 MB
    double* lg     = (double*)(ws + (18u << 20));                // 256 KB + 8 B
    int*    c1     = (int*)(ws + (18u << 20) + (512u << 10));    // 2 KB
    int*    done   = (int*)(ws + (18u << 20) + (516u << 10));    // 4 B
    double* bsum   = (double*)(ws + (18u << 20) + (576u << 10)); // 4 KB
    int*    bcnt   = (int*)(ws + (18u << 20) + (640u << 10));    // 2 KB

    pack_kernel<<<512, 256, 0, stream>>>(bits, packed, lg, c1, done);
    gram_kernel<<<NT32 * NSLICE, 64, 0, stream>>>(packed, Cp, c1);
    mi_kernel<<<MIGRID, 256, 0, stream>>>(Cp, c1, lg, bsum, bcnt, done, (float*)d_out);
}